// Round 13
// baseline (434.793 us; speedup 1.0000x reference)
//
#include <hip/hip_runtime.h>
#include <math.h>

#define H 4096
#define E 64
#define T_TOTAL 32768
#define TB 128            // tokens per block
#define NT 256            // 4 waves; tg = tid&15 (token octet), eg = tid>>4 (expert quad)
#define KC 64             // K per chunk
#define NCH (H / KC)      // 64 chunks
#define OFF_W 2097152
#define OFF_I 2162688

#define AS1 __attribute__((address_space(1)))
#define AS3 __attribute__((address_space(3)))

// Proven (R9/R12 passed): 16B global->LDS DMA, linear LDS dest.
#define GLD16(SRC, DST)                                                      \
  __builtin_amdgcn_global_load_lds((const AS1 void*)(SRC), (AS3 void*)(DST), \
                                   16, 0, 0)

// Bank swizzle (R12-proven): logical col4 c of row r stored at slot c ^ swz(r).
__device__ __forceinline__ int swz(int row) { return (row ^ (row >> 4)) & 15; }

__global__ __launch_bounds__(NT, 1)   // 1 block/CU target -> VGPR cap 512, no spill
void moe_router_kernel(const float* __restrict__ x,
                       const float* __restrict__ W,
                       float* __restrict__ out)
{
    // Double-buffered tiles, [rows][16 slots of 16B], slot-swizzled. 96 KB.
    __shared__ float xt[2][TB * KC];   // 2 x 32 KB
    __shared__ float wt[2][E * KC];    // 2 x 16 KB

    const int tid  = threadIdx.x;
    const int tg   = tid & 15;          // token octet 8tg..8tg+7
    const int eg   = tid >> 4;          // expert quad 4eg..4eg+3
    const int tok0 = blockIdx.x * TB;

    // ---- DMA source maps (rule 21: linear dest unit u, inverse-swz source) ----
    // x: unit u (0..2047): row = u>>4 (0..127), slot = u&15, col4 = slot ^ swz(row)
    const float* xsrc[8];
    int xdst[8];
#pragma unroll
    for (int k = 0; k < 8; ++k) {
        const int u   = tid + k * NT;
        const int row = u >> 4;
        const int c4  = (u & 15) ^ swz(row);
        xsrc[k] = x + (size_t)(tok0 + row) * H + (c4 << 2);
        xdst[k] = u * 4;
    }
    // W: unit u (0..1023): row = u>>4 (0..63)
    const float* wsrc[4];
    int wdst[4];
#pragma unroll
    for (int k = 0; k < 4; ++k) {
        const int u   = tid + k * NT;
        const int row = u >> 4;
        const int c4  = (u & 15) ^ swz(row);
        wsrc[k] = W + (size_t)row * H + (c4 << 2);
        wdst[k] = u * 4;
    }

    // ---- LDS read bases (float idx; step s reads base ^ (4*s), carry-free) ----
    int xbase[8], wbase[4];
#pragma unroll
    for (int i = 0; i < 8; ++i) {
        const int r = 8 * tg + i;
        xbase[i] = r * KC + (swz(r) << 2);
    }
#pragma unroll
    for (int j = 0; j < 4; ++j) {
        const int r = 4 * eg + j;
        wbase[j] = r * KC + (swz(r) << 2);
    }

    float acc[8][4];
#pragma unroll
    for (int i = 0; i < 8; ++i)
#pragma unroll
        for (int j = 0; j < 4; ++j) acc[i][j] = 0.f;

    // ---- prologue: DMA chunk 0 into buffer 0 ----
#pragma unroll
    for (int k = 0; k < 8; ++k) GLD16(xsrc[k], &xt[0][xdst[k]]);
#pragma unroll
    for (int k = 0; k < 4; ++k) GLD16(wsrc[k], &wt[0][wdst[k]]);
    __syncthreads();   // compiler emits vmcnt(0) drain before s_barrier

    for (int c = 0; c < NCH; ++c) {
        const int b = c & 1;

        // DMA next chunk into the other buffer (retired by the barrier below)
        if (c + 1 < NCH) {
#pragma unroll
            for (int k = 0; k < 8; ++k)
                GLD16(xsrc[k] + (c + 1) * KC, &xt[b ^ 1][xdst[k]]);
#pragma unroll
            for (int k = 0; k < 4; ++k)
                GLD16(wsrc[k] + (c + 1) * KC, &wt[b ^ 1][wdst[k]]);
        }

        // ---- compute 16 K4 steps from buffer b ----
        const float* xp = &xt[b][0];
        const float* wp = &wt[b][0];
#pragma unroll
        for (int s = 0; s < 16; ++s) {
            float4 xv[8], wv[4];
#pragma unroll
            for (int i = 0; i < 8; ++i)
                xv[i] = *(const float4*)(xp + (xbase[i] ^ (4 * s)));
#pragma unroll
            for (int j = 0; j < 4; ++j)
                wv[j] = *(const float4*)(wp + (wbase[j] ^ (4 * s)));
            // ascending-K, x/y/z/w per (token,expert) — bit-identical chain
            // to the verified R1/R5/R6/R12 kernels (index tie-safety).
#pragma unroll
            for (int i = 0; i < 8; ++i)
#pragma unroll
                for (int j = 0; j < 4; ++j) {
                    acc[i][j] = fmaf(xv[i].x, wv[j].x, acc[i][j]);
                    acc[i][j] = fmaf(xv[i].y, wv[j].y, acc[i][j]);
                    acc[i][j] = fmaf(xv[i].z, wv[j].z, acc[i][j]);
                    acc[i][j] = fmaf(xv[i].w, wv[j].w, acc[i][j]);
                }
        }

        __syncthreads();   // chunk c done everywhere; chunk c+1 DMA retired
    }

    // ---- logits out (coalesced float4 per owned token) ----
#pragma unroll
    for (int i = 0; i < 8; ++i) {
        float4 v; v.x = acc[i][0]; v.y = acc[i][1]; v.z = acc[i][2]; v.w = acc[i][3];
        *(float4*)(out + (size_t)(tok0 + 8 * tg + i) * E + 4 * eg) = v;
    }

    // ---- exchange for top-2 (reuse xt; 128 x 65 tile = 33.3 KB) ----
    float* lt = &xt[0][0];
#pragma unroll
    for (int i = 0; i < 8; ++i)
#pragma unroll
        for (int j = 0; j < 4; ++j)
            lt[(8 * tg + i) * 65 + 4 * eg + j] = acc[i][j];
    __syncthreads();

    if (tid < TB) {
        const float* row = lt + tid * 65;
        float v1 = -INFINITY, v2 = -INFINITY;
        int i1 = 0, i2 = 0;
        for (int e = 0; e < E; ++e) {
            float v = row[e];
            if (v > v1)      { v2 = v1; i2 = i1; v1 = v; i1 = e; }
            else if (v > v2) { v2 = v;  i2 = e; }
        }
        // softmax -> top2 -> renorm == sigmoid of logit gap (Z cancels)
        float ee = expf(v2 - v1);
        float w1 = 1.0f / (1.0f + ee);
        float w2 = ee * w1;

        const size_t tok = (size_t)tok0 + tid;
        out[OFF_W + tok * 2]     = w1;
        out[OFF_W + tok * 2 + 1] = w2;
        out[OFF_I + tok * 2]     = (float)i1;
        out[OFF_I + tok * 2 + 1] = (float)i2;
    }
}

extern "C" void kernel_launch(void* const* d_in, const int* in_sizes, int n_in,
                              void* d_out, int out_size, void* d_ws, size_t ws_size,
                              hipStream_t stream) {
    const float* x = (const float*)d_in[0];
    const float* W = (const float*)d_in[1];
    float* out = (float*)d_out;

    dim3 grid(T_TOTAL / TB);   // 256 blocks -> exactly 1 block/CU
    dim3 block(NT);
    moe_router_kernel<<<grid, block, 0, stream>>>(x, W, out);
}